// Round 17
// baseline (237.620 us; speedup 1.0000x reference)
//
#include <hip/hip_runtime.h>

#define NB 256      // batch
#define TT 200      // time steps
#define DD 1250     // input dim
#define H1 100
#define H2 20
#define NO 2

// ---- GEMM kernel geometry: C[51200,100] = Xflat[51200,1250] @ Wih1^T ----
#define BM 64                 // rows per block
#define GRID_A (51200 / BM)   // 800
#define KC 64                 // K-chunk
#define NCH 20                // 1280 / 64 (K padded)
#define WR 112                // padded W rows (7 n-tiles of 16)
#define KPAD 1280

typedef __attribute__((ext_vector_type(4))) float f32x4;
typedef __attribute__((ext_vector_type(8))) short s16x8;

__device__ __forceinline__ unsigned short f2bf(float f) {
    unsigned u = __builtin_bit_cast(unsigned, f);
    u += 0x7FFFu + ((u >> 16) & 1u);          // round-to-nearest-even
    return (unsigned short)(u >> 16);
}
__device__ __forceinline__ float bf2f(unsigned short s) {
    unsigned u = ((unsigned)s) << 16;
    return __builtin_bit_cast(float, u);
}

#define GLL(srcp, dstp) __builtin_amdgcn_global_load_lds( \
    (const __attribute__((address_space(1))) void*)(srcp), \
    (__attribute__((address_space(3))) void*)(dstp), 16, 0, 0)

// ============ kernel 0: Wih1 fp32[100][1250] -> bf16 [112][1280] (padded) ====
__global__ void prep_w(const float* __restrict__ Wih1, unsigned short* __restrict__ w_ws)
{
    const int idx = blockIdx.x * 256 + threadIdx.x;     // uint2 (4-short) granules
    if (idx >= WR * KPAD / 4) return;
    const int r  = idx / (KPAD / 4);
    const int k4 = (idx - r * (KPAD / 4)) * 4;
    unsigned short o[4];
    #pragma unroll
    for (int e = 0; e < 4; ++e) {
        const int k = k4 + e;
        o[e] = (r < H1 && k < DD) ? f2bf(Wih1[r * DD + k]) : (unsigned short)0;
    }
    uint2 pk;
    pk.x = (unsigned)o[0] | ((unsigned)o[1] << 16);
    pk.y = (unsigned)o[2] | ((unsigned)o[3] << 16);
    *(uint2*)&w_ws[r * KPAD + k4] = pk;
}

// ============ kernel 1: pre1[b*TT+t][h] via MFMA — global_load_lds staging ===
// (r16 exact, proven: async DMA staging + pre-swizzled source / swizzled read)
__launch_bounds__(256, 4)
__global__ void gemm_pre(const float* __restrict__ x,
                         const unsigned short* __restrict__ w_ws,
                         unsigned short* __restrict__ preT)
{
    __shared__ __align__(16) float          a_sf[2][BM * 64];   // 32768 B
    __shared__ __align__(16) unsigned short w_sh[2][WR * 64];   // 28672 B

    const int tid = threadIdx.x;
    const int bid = blockIdx.x;
    const int wv  = tid >> 6;
    const int ln  = tid & 63;
    const int c16 = ln & 15;
    const int kgrp = ln >> 4;                 // 0..3

    f32x4 acc[7];
    #pragma unroll
    for (int i = 0; i < 7; ++i)
        #pragma unroll
        for (int c = 0; c < 4; ++c) acc[i][c] = 0.f;

    auto agll = [&](int k0, int buf) {
        #pragma unroll
        for (int q = 0; q < 4; ++q) {
            const int idx  = tid + q * 256;
            const int row  = idx >> 4;
            const int segp = idx & 15;
            const int segl = segp ^ (row & 15);            // inverse swizzle
            const float* src = x + (size_t)(bid * BM + row) * DD + k0 + segl * 4;
            GLL(src, &a_sf[buf][idx * 4]);
        }
    };
    auto wgll = [&](int k0, int buf) {
        #pragma unroll
        for (int q = 0; q < 4; ++q) {
            const int idx = tid + q * 256;
            if (idx < WR * 8) {
                const int row = idx >> 3;
                const int c8p = idx & 7;
                const int c8l = c8p ^ (row & 7);           // inverse swizzle
                const unsigned short* src = w_ws + row * KPAD + k0 + c8l * 8;
                GLL(src, &w_sh[buf][idx * 8]);
            }
        }
    };

    auto mfma_chunk = [&](int buf) {
        #pragma unroll
        for (int s = 0; s < 2; ++s) {
            const int row_a = wv * 16 + c16;
            const int sb = s * 8 + kgrp * 2;               // logical seg base
            const int sp0 = (sb + 0) ^ (row_a & 15);
            const int sp1 = (sb + 1) ^ (row_a & 15);
            const float4 av0 = *(const float4*)&a_sf[buf][row_a * 64 + sp0 * 4];
            const float4 av1 = *(const float4*)&a_sf[buf][row_a * 64 + sp1 * 4];
            const s16x8 af = {
                (short)f2bf(av0.x), (short)f2bf(av0.y),
                (short)f2bf(av0.z), (short)f2bf(av0.w),
                (short)f2bf(av1.x), (short)f2bf(av1.y),
                (short)f2bf(av1.z), (short)f2bf(av1.w) };
            #pragma unroll
            for (int nt = 0; nt < 7; ++nt) {
                const int row_b = nt * 16 + c16;
                const int c8  = s * 4 + kgrp;              // logical
                const int c8p = c8 ^ (row_b & 7);
                const s16x8 bf = *(const s16x8*)&w_sh[buf][row_b * 64 + c8p * 8];
                acc[nt] = __builtin_amdgcn_mfma_f32_16x16x32_bf16(af, bf, acc[nt], 0, 0, 0);
            }
        }
    };

    // tail chunk 19 (k 1216..1279, valid < 1250): guarded register loads
    float4 ta[4];
    #pragma unroll
    for (int q = 0; q < 4; ++q) {
        const int idx  = tid + q * 256;
        const int row  = idx >> 4;
        const int segl = idx & 15;
        const int gk   = 19 * KC + segl * 4;
        const float* xp = x + (size_t)(bid * BM + row) * DD + gk;
        float4 v;
        v.x = (gk + 0 < DD) ? xp[0] : 0.f;
        v.y = (gk + 1 < DD) ? xp[1] : 0.f;
        v.z = (gk + 2 < DD) ? xp[2] : 0.f;
        v.w = (gk + 3 < DD) ? xp[3] : 0.f;
        ta[q] = v;
    }

    agll(0, 0);
    wgll(0, 0);

    for (int kc = 0; kc < 19; ++kc) {
        const int buf = kc & 1;
        __syncthreads();                      // chunk kc resident in LDS[buf]
        if (kc + 1 < 19) agll((kc + 1) * KC, buf ^ 1);
        wgll((kc + 1) * KC, buf ^ 1);         // kc+1 == 19 ok (W padded)
        mfma_chunk(buf);
    }

    // tail: A via swizzled ds_write into buf 1
    #pragma unroll
    for (int q = 0; q < 4; ++q) {
        const int idx  = tid + q * 256;
        const int row  = idx >> 4;
        const int segl = idx & 15;
        const int sp   = segl ^ (row & 15);
        *(float4*)&a_sf[1][row * 64 + sp * 4] = ta[q];
    }
    __syncthreads();                          // publishes A-tail + W chunk 19
    mfma_chunk(1);

    // C/D layout: col = l&15, row = (l>>4)*4 + reg  (m89-verified)
    const int rg = bid * BM + wv * 16 + (kgrp << 2);        // global C row base
    #pragma unroll
    for (int nt = 0; nt < 7; ++nt) {
        const int col = nt * 16 + c16;
        if (col < H1) {
            #pragma unroll
            for (int r = 0; r < 4; ++r)
                preT[(size_t)(rg + r) * H1 + col] = f2bf(acc[nt][r]);
        }
    }
}

// ============ kernel 2: two-layer scan + FC, TWO BATCHES PER BLOCK ===========
// r16 analysis: scan per-step 1260cy is fixed overhead (barrier skew + LDS
// write->read turnaround), not issue (VALUBusy 17%). Dot restructurings
// (r11/r12/r14) all neutral. Amortize: each block advances TWO independent
// batch recurrences per barrier; weights shared, chains overlap.
#define FMA4(W, PTR) { const float4 hv_ = *(const float4*)(PTR);            \
    a0 = fmaf((W).x, hv_.x, a0); a1 = fmaf((W).y, hv_.y, a1);               \
    a2 = fmaf((W).z, hv_.z, a2); a3 = fmaf((W).w, hv_.w, a3); }

#define CH 8        // steps per chunk
#define NCHK 25     // 200 / 8

__launch_bounds__(320, 1)
__global__ void scan_rnn(const unsigned short* __restrict__ preT,
                         const float* __restrict__ Whh1,
                         const float* __restrict__ bih1,
                         const float* __restrict__ bhh1,
                         const float* __restrict__ Wih2,
                         const float* __restrict__ Whh2,
                         const float* __restrict__ bih2,
                         const float* __restrict__ bhh2,
                         const float* __restrict__ Wfc,
                         const float* __restrict__ bfc,
                         const float* __restrict__ mask1,
                         const float* __restrict__ mask2,
                         float* __restrict__ out)
{
    __shared__ alignas(16) float h1_s[2][2][104];     // [batch][dbuf][..], pad zeroed
    __shared__ alignas(16) float c_s[2][2][120];      // [0..99]=o1, [100..119]=h2
    __shared__ alignas(16) float h2f_s[2][H2];
    __shared__ alignas(16) float m_lds[2][2][CH * H1];    // [batch][buf][..]
    __shared__ alignas(16) float p_lds[2][2][CH * H1];

    const int tid = threadIdx.x;
    const int b0  = blockIdx.x * 2;
    const float* m1b[2] = { mask1 + (size_t)(b0 + 0) * TT * H1,
                            mask1 + (size_t)(b0 + 1) * TT * H1 };
    const unsigned short* pTb[2] = { preT + (size_t)(b0 + 0) * TT * H1,
                                     preT + (size_t)(b0 + 1) * TT * H1 };

    const int h = tid >> 1;
    const int p = tid & 1;
    const bool l1t = (tid < 200);
    const bool l2t = (tid >= 256 && tid < 256 + 2 * H2);   // wave 4 only
    const int k2 = (tid - 256) >> 1;
    const int p3 = (tid - 256) & 1;

    float4 w00{}, w01{}, w02{}, w03{}, w04{}, w05{}, w06{}, w07{},
           w08{}, w09{}, w10{}, w11{}, w12{}, w13{}, w14{};
    float b1 = 0.f, b2 = 0.f;

    if (l1t) {
        const float* wr = Whh1 + h * H1 + p * 52;
        w00 = *(const float4*)(wr +  0); w01 = *(const float4*)(wr +  4);
        w02 = *(const float4*)(wr +  8); w03 = *(const float4*)(wr + 12);
        w04 = *(const float4*)(wr + 16); w05 = *(const float4*)(wr + 20);
        w06 = *(const float4*)(wr + 24); w07 = *(const float4*)(wr + 28);
        w08 = *(const float4*)(wr + 32); w09 = *(const float4*)(wr + 36);
        w10 = *(const float4*)(wr + 40); w11 = *(const float4*)(wr + 44);
        if (p == 0) { w12 = *(const float4*)(wr + 48); b1 = bih1[h] + bhh1[h]; }
    } else if (l2t) {
        if (p3 == 0) {
            const float* wr = Wih2 + k2 * H1;           // [0..59]
            w00 = *(const float4*)(wr +  0); w01 = *(const float4*)(wr +  4);
            w02 = *(const float4*)(wr +  8); w03 = *(const float4*)(wr + 12);
            w04 = *(const float4*)(wr + 16); w05 = *(const float4*)(wr + 20);
            w06 = *(const float4*)(wr + 24); w07 = *(const float4*)(wr + 28);
            w08 = *(const float4*)(wr + 32); w09 = *(const float4*)(wr + 36);
            w10 = *(const float4*)(wr + 40); w11 = *(const float4*)(wr + 44);
            w12 = *(const float4*)(wr + 48); w13 = *(const float4*)(wr + 52);
            w14 = *(const float4*)(wr + 56);
            b2 = bih2[k2] + bhh2[k2];
        } else {
            const float* wr = Wih2 + k2 * H1 + 60;      // [60..99]
            w00 = *(const float4*)(wr +  0); w01 = *(const float4*)(wr +  4);
            w02 = *(const float4*)(wr +  8); w03 = *(const float4*)(wr + 12);
            w04 = *(const float4*)(wr + 16); w05 = *(const float4*)(wr + 20);
            w06 = *(const float4*)(wr + 24); w07 = *(const float4*)(wr + 28);
            w08 = *(const float4*)(wr + 32); w09 = *(const float4*)(wr + 36);
            const float* wh = Whh2 + k2 * H2;           // h2 part [100..119]
            w10 = *(const float4*)(wh +  0); w11 = *(const float4*)(wh +  4);
            w12 = *(const float4*)(wh +  8); w13 = *(const float4*)(wh + 12);
            w14 = *(const float4*)(wh + 16);
        }
    }

    for (int i = tid; i < 104; i += 320) {
        h1_s[0][0][i] = 0.f; h1_s[0][1][i] = 0.f;
        h1_s[1][0][i] = 0.f; h1_s[1][1][i] = 0.f;
    }
    for (int i = tid; i < 120; i += 320) {
        c_s[0][0][i] = 0.f; c_s[0][1][i] = 0.f;
        c_s[1][0][i] = 0.f; c_s[1][1][i] = 0.f;
    }

    // stage chunk 0 into buffer 0 for both batches
    if (tid < 200) {
        *(float4*)&m_lds[0][0][tid * 4] = *(const float4*)&m1b[0][tid * 4];
        *(float4*)&m_lds[1][0][tid * 4] = *(const float4*)&m1b[1][tid * 4];
    } else if (tid < 300) {
        #pragma unroll
        for (int bb = 0; bb < 2; ++bb) {
            const s16x8 pv = *(const s16x8*)&pTb[bb][(tid - 200) * 8];
            float* dst = &p_lds[bb][0][(tid - 200) * 8];
            *(float4*)dst       = make_float4(bf2f(pv[0]), bf2f(pv[1]), bf2f(pv[2]), bf2f(pv[3]));
            *(float4*)(dst + 4) = make_float4(bf2f(pv[4]), bf2f(pv[5]), bf2f(pv[6]), bf2f(pv[7]));
        }
    }
    __syncthreads();

    int buf = 0;
    for (int c = 0; c < NCHK; ++c) {
        const bool more = (c + 1 < NCHK);
        float4 mstA{}, mstB{}; s16x8 pstA{}, pstB{};

        #pragma unroll
        for (int u = 0; u < CH; ++u) {
            const int t = c * CH + u;
            const int cur = t & 1, nxt = cur ^ 1;

            if (u > 0) __syncthreads();

            if (u == 0 && more) {              // issue next chunk's loads
                const int base = (c + 1) * (CH * H1);
                if (tid < 200) {
                    mstA = *(const float4*)&m1b[0][base + tid * 4];
                    mstB = *(const float4*)&m1b[1][base + tid * 4];
                } else if (tid < 300) {
                    pstA = *(const s16x8*)&pTb[0][base + (tid - 200) * 8];
                    pstB = *(const s16x8*)&pTb[1][base + (tid - 200) * 8];
                }
            }

            if (l1t) {
                #pragma unroll
                for (int bb = 0; bb < 2; ++bb) {
                    float a0 = (p == 0) ? (p_lds[bb][buf][u * H1 + h] + b1) : 0.f;
                    const float mv = (p == 1) ? m_lds[bb][buf][u * H1 + h] : 0.f;
                    float a1 = 0.f, a2 = 0.f, a3 = 0.f;
                    const float* hb = &h1_s[bb][cur][p * 52];
                    FMA4(w00, hb +  0); FMA4(w01, hb +  4); FMA4(w02, hb +  8);
                    FMA4(w03, hb + 12); FMA4(w04, hb + 16); FMA4(w05, hb + 20);
                    FMA4(w06, hb + 24); FMA4(w07, hb + 28); FMA4(w08, hb + 32);
                    FMA4(w09, hb + 36); FMA4(w10, hb + 40); FMA4(w11, hb + 44);
                    FMA4(w12, hb + 48);
                    float part = (a0 + a1) + (a2 + a3);
                    float tot  = part + __shfl_xor(part, 1);
                    tot = fmaxf(tot, 0.f);                       // h1(t)
                    if (p == 0) h1_s[bb][nxt][h] = tot;
                    else        c_s[bb][nxt][h] = tot * mv;      // o1(t)
                }
            }

            if (l2t && t >= 1) {
                #pragma unroll
                for (int bb = 0; bb < 2; ++bb) {
                    float a0 = (p3 == 0) ? b2 : 0.f;
                    float a1 = 0.f, a2 = 0.f, a3 = 0.f;
                    const float* cb = &c_s[bb][cur][p3 * 60];
                    FMA4(w00, cb +  0); FMA4(w01, cb +  4); FMA4(w02, cb +  8);
                    FMA4(w03, cb + 12); FMA4(w04, cb + 16); FMA4(w05, cb + 20);
                    FMA4(w06, cb + 24); FMA4(w07, cb + 28); FMA4(w08, cb + 32);
                    FMA4(w09, cb + 36); FMA4(w10, cb + 40); FMA4(w11, cb + 44);
                    FMA4(w12, cb + 48); FMA4(w13, cb + 52); FMA4(w14, cb + 56);
                    float part = (a0 + a1) + (a2 + a3);
                    part += __shfl_xor(part, 1);
                    const float h2v = fmaxf(part, 0.f);          // h2(t-1)
                    if (p3 == 0) c_s[bb][nxt][100 + k2] = h2v;
                }
            }
        }

        if (more) {
            if (tid < 200) {
                *(float4*)&m_lds[0][buf ^ 1][tid * 4] = mstA;
                *(float4*)&m_lds[1][buf ^ 1][tid * 4] = mstB;
            } else if (tid < 300) {
                float* dA = &p_lds[0][buf ^ 1][(tid - 200) * 8];
                *(float4*)dA       = make_float4(bf2f(pstA[0]), bf2f(pstA[1]), bf2f(pstA[2]), bf2f(pstA[3]));
                *(float4*)(dA + 4) = make_float4(bf2f(pstA[4]), bf2f(pstA[5]), bf2f(pstA[6]), bf2f(pstA[7]));
                float* dB = &p_lds[1][buf ^ 1][(tid - 200) * 8];
                *(float4*)dB       = make_float4(bf2f(pstB[0]), bf2f(pstB[1]), bf2f(pstB[2]), bf2f(pstB[3]));
                *(float4*)(dB + 4) = make_float4(bf2f(pstB[4]), bf2f(pstB[5]), bf2f(pstB[6]), bf2f(pstB[7]));
            }
            buf ^= 1;
        }
        __syncthreads();                        // chunk boundary barrier
    }

    // epilogue t = TT: layer2 computes h2(199) for both batches
    {
        const int cur = TT & 1;                              // 0
        if (l2t) {
            #pragma unroll
            for (int bb = 0; bb < 2; ++bb) {
                float a0 = (p3 == 0) ? b2 : 0.f;
                float a1 = 0.f, a2 = 0.f, a3 = 0.f;
                const float* cb = &c_s[bb][cur][p3 * 60];
                FMA4(w00, cb +  0); FMA4(w01, cb +  4); FMA4(w02, cb +  8);
                FMA4(w03, cb + 12); FMA4(w04, cb + 16); FMA4(w05, cb + 20);
                FMA4(w06, cb + 24); FMA4(w07, cb + 28); FMA4(w08, cb + 32);
                FMA4(w09, cb + 36); FMA4(w10, cb + 40); FMA4(w11, cb + 44);
                FMA4(w12, cb + 48); FMA4(w13, cb + 52); FMA4(w14, cb + 56);
                float part = (a0 + a1) + (a2 + a3);
                part += __shfl_xor(part, 1);
                if (p3 == 0) h2f_s[bb][k2] = fmaxf(part, 0.f);   // h2(199)
            }
        }
        __syncthreads();
    }

    if (tid < 2 * NO) {
        const int bb = tid >> 1;
        const int o  = tid & 1;
        const float* m2 = mask2 + ((size_t)(b0 + bb) * TT + (TT - 1)) * H2;
        float s = bfc[o];
        #pragma unroll
        for (int k = 0; k < H2; ++k)
            s = fmaf(Wfc[o * H2 + k], h2f_s[bb][k] * m2[k], s);
        out[(b0 + bb) * NO + o] = s;
    }
}

extern "C" void kernel_launch(void* const* d_in, const int* in_sizes, int n_in,
                              void* d_out, int out_size, void* d_ws, size_t ws_size,
                              hipStream_t stream) {
    const float* x     = (const float*)d_in[0];
    const float* Wih1  = (const float*)d_in[1];
    const float* Whh1  = (const float*)d_in[2];
    const float* bih1  = (const float*)d_in[3];
    const float* bhh1  = (const float*)d_in[4];
    const float* Wih2  = (const float*)d_in[5];
    const float* Whh2  = (const float*)d_in[6];
    const float* bih2  = (const float*)d_in[7];
    const float* bhh2  = (const float*)d_in[8];
    const float* Wfc   = (const float*)d_in[9];
    const float* bfc   = (const float*)d_in[10];
    const float* mask1 = (const float*)d_in[11];
    const float* mask2 = (const float*)d_in[12];
    float* out = (float*)d_out;

    unsigned short* preT = (unsigned short*)d_ws;                     // 10,240,000 B
    unsigned short* w_ws = (unsigned short*)((char*)d_ws + 10240000); //    286,720 B

    prep_w  <<<dim3((WR * KPAD / 4 + 255) / 256), dim3(256), 0, stream>>>(Wih1, w_ws);
    gemm_pre<<<dim3(GRID_A), dim3(256), 0, stream>>>(x, w_ws, preT);
    scan_rnn<<<dim3(NB / 2), dim3(320), 0, stream>>>(preT, Whh1, bih1, bhh1,
                                                     Wih2, Whh2, bih2, bhh2,
                                                     Wfc, bfc, mask1, mask2, out);
}

// Round 18
// 169.167 us; speedup vs baseline: 1.4046x; 1.4046x over previous
//
#include <hip/hip_runtime.h>

#define NB 256      // batch
#define TT 200      // time steps
#define DD 1250     // input dim
#define H1 100
#define H2 20
#define NO 2

// ---- GEMM kernel geometry: C[51200,100] = Xflat[51200,1250] @ Wih1^T ----
#define BM 64                 // rows per block
#define GRID_A (51200 / BM)   // 800
#define KC 64                 // K-chunk
#define NCH 20                // 1280 / 64 (K padded)
#define WR 112                // padded W rows (7 n-tiles of 16)
#define KPAD 1280

typedef __attribute__((ext_vector_type(4))) float f32x4;
typedef __attribute__((ext_vector_type(8))) short s16x8;

__device__ __forceinline__ unsigned short f2bf(float f) {
    unsigned u = __builtin_bit_cast(unsigned, f);
    u += 0x7FFFu + ((u >> 16) & 1u);          // round-to-nearest-even
    return (unsigned short)(u >> 16);
}
__device__ __forceinline__ float bf2f(unsigned short s) {
    unsigned u = ((unsigned)s) << 16;
    return __builtin_bit_cast(float, u);
}

#define GLL(srcp, dstp) __builtin_amdgcn_global_load_lds( \
    (const __attribute__((address_space(1))) void*)(srcp), \
    (__attribute__((address_space(3))) void*)(dstp), 16, 0, 0)

// Fenceless per-step barrier: LDS visibility only (lgkmcnt(0) + s_barrier,
// cdna4_isa §8 pattern). No vmcnt drain -> chunk-staging global loads stay
// in flight across steps. sched_barrier(0) pins ordering (rule #18).
#define STEP_BARRIER() do {                                             \
    asm volatile("s_waitcnt lgkmcnt(0)\n\ts_barrier" ::: "memory");     \
    __builtin_amdgcn_sched_barrier(0);                                  \
} while (0)

// ============ kernel 0: Wih1 fp32[100][1250] -> bf16 [112][1280] (padded) ====
__global__ void prep_w(const float* __restrict__ Wih1, unsigned short* __restrict__ w_ws)
{
    const int idx = blockIdx.x * 256 + threadIdx.x;     // uint2 (4-short) granules
    if (idx >= WR * KPAD / 4) return;
    const int r  = idx / (KPAD / 4);
    const int k4 = (idx - r * (KPAD / 4)) * 4;
    unsigned short o[4];
    #pragma unroll
    for (int e = 0; e < 4; ++e) {
        const int k = k4 + e;
        o[e] = (r < H1 && k < DD) ? f2bf(Wih1[r * DD + k]) : (unsigned short)0;
    }
    uint2 pk;
    pk.x = (unsigned)o[0] | ((unsigned)o[1] << 16);
    pk.y = (unsigned)o[2] | ((unsigned)o[3] << 16);
    *(uint2*)&w_ws[r * KPAD + k4] = pk;
}

// ============ kernel 1: pre1[b*TT+t][h] via MFMA — global_load_lds staging ===
// (r16 exact, proven: async DMA staging + pre-swizzled source / swizzled read)
__launch_bounds__(256, 4)
__global__ void gemm_pre(const float* __restrict__ x,
                         const unsigned short* __restrict__ w_ws,
                         unsigned short* __restrict__ preT)
{
    __shared__ __align__(16) float          a_sf[2][BM * 64];   // 32768 B
    __shared__ __align__(16) unsigned short w_sh[2][WR * 64];   // 28672 B

    const int tid = threadIdx.x;
    const int bid = blockIdx.x;
    const int wv  = tid >> 6;
    const int ln  = tid & 63;
    const int c16 = ln & 15;
    const int kgrp = ln >> 4;                 // 0..3

    f32x4 acc[7];
    #pragma unroll
    for (int i = 0; i < 7; ++i)
        #pragma unroll
        for (int c = 0; c < 4; ++c) acc[i][c] = 0.f;

    auto agll = [&](int k0, int buf) {
        #pragma unroll
        for (int q = 0; q < 4; ++q) {
            const int idx  = tid + q * 256;
            const int row  = idx >> 4;
            const int segp = idx & 15;
            const int segl = segp ^ (row & 15);            // inverse swizzle
            const float* src = x + (size_t)(bid * BM + row) * DD + k0 + segl * 4;
            GLL(src, &a_sf[buf][idx * 4]);
        }
    };
    auto wgll = [&](int k0, int buf) {
        #pragma unroll
        for (int q = 0; q < 4; ++q) {
            const int idx = tid + q * 256;
            if (idx < WR * 8) {
                const int row = idx >> 3;
                const int c8p = idx & 7;
                const int c8l = c8p ^ (row & 7);           // inverse swizzle
                const unsigned short* src = w_ws + row * KPAD + k0 + c8l * 8;
                GLL(src, &w_sh[buf][idx * 8]);
            }
        }
    };

    auto mfma_chunk = [&](int buf) {
        #pragma unroll
        for (int s = 0; s < 2; ++s) {
            const int row_a = wv * 16 + c16;
            const int sb = s * 8 + kgrp * 2;               // logical seg base
            const int sp0 = (sb + 0) ^ (row_a & 15);
            const int sp1 = (sb + 1) ^ (row_a & 15);
            const float4 av0 = *(const float4*)&a_sf[buf][row_a * 64 + sp0 * 4];
            const float4 av1 = *(const float4*)&a_sf[buf][row_a * 64 + sp1 * 4];
            const s16x8 af = {
                (short)f2bf(av0.x), (short)f2bf(av0.y),
                (short)f2bf(av0.z), (short)f2bf(av0.w),
                (short)f2bf(av1.x), (short)f2bf(av1.y),
                (short)f2bf(av1.z), (short)f2bf(av1.w) };
            #pragma unroll
            for (int nt = 0; nt < 7; ++nt) {
                const int row_b = nt * 16 + c16;
                const int c8  = s * 4 + kgrp;              // logical
                const int c8p = c8 ^ (row_b & 7);
                const s16x8 bf = *(const s16x8*)&w_sh[buf][row_b * 64 + c8p * 8];
                acc[nt] = __builtin_amdgcn_mfma_f32_16x16x32_bf16(af, bf, acc[nt], 0, 0, 0);
            }
        }
    };

    // tail chunk 19 (k 1216..1279, valid < 1250): guarded register loads
    float4 ta[4];
    #pragma unroll
    for (int q = 0; q < 4; ++q) {
        const int idx  = tid + q * 256;
        const int row  = idx >> 4;
        const int segl = idx & 15;
        const int gk   = 19 * KC + segl * 4;
        const float* xp = x + (size_t)(bid * BM + row) * DD + gk;
        float4 v;
        v.x = (gk + 0 < DD) ? xp[0] : 0.f;
        v.y = (gk + 1 < DD) ? xp[1] : 0.f;
        v.z = (gk + 2 < DD) ? xp[2] : 0.f;
        v.w = (gk + 3 < DD) ? xp[3] : 0.f;
        ta[q] = v;
    }

    agll(0, 0);
    wgll(0, 0);

    for (int kc = 0; kc < 19; ++kc) {
        const int buf = kc & 1;
        __syncthreads();                      // chunk kc resident in LDS[buf]
        if (kc + 1 < 19) agll((kc + 1) * KC, buf ^ 1);
        wgll((kc + 1) * KC, buf ^ 1);         // kc+1 == 19 ok (W padded)
        mfma_chunk(buf);
    }

    // tail: A via swizzled ds_write into buf 1
    #pragma unroll
    for (int q = 0; q < 4; ++q) {
        const int idx  = tid + q * 256;
        const int row  = idx >> 4;
        const int segl = idx & 15;
        const int sp   = segl ^ (row & 15);
        *(float4*)&a_sf[1][row * 64 + sp * 4] = ta[q];
    }
    __syncthreads();                          // publishes A-tail + W chunk 19
    mfma_chunk(1);

    // C/D layout: col = l&15, row = (l>>4)*4 + reg  (m89-verified)
    const int rg = bid * BM + wv * 16 + (kgrp << 2);        // global C row base
    #pragma unroll
    for (int nt = 0; nt < 7; ++nt) {
        const int col = nt * 16 + c16;
        if (col < H1) {
            #pragma unroll
            for (int r = 0; r < 4; ++r)
                preT[(size_t)(rg + r) * H1 + col] = f2bf(acc[nt][r]);
        }
    }
}

// ============ kernel 2: fused two-layer scan + FC (r13 + fenceless barriers) =
// r17 decomposition: per-step = ~400cy overhead + ~860cy dot (LDS-instr-rate).
// This round removes the vmcnt(0) drain from the 7 in-chunk barriers per
// chunk: per-step sync only needs LDS visibility (lgkmcnt(0)+s_barrier);
// the full __syncthreads stays at chunk boundaries.
#define FMA4(W, PTR) { const float4 hv_ = *(const float4*)(PTR);            \
    a0 = fmaf((W).x, hv_.x, a0); a1 = fmaf((W).y, hv_.y, a1);               \
    a2 = fmaf((W).z, hv_.z, a2); a3 = fmaf((W).w, hv_.w, a3); }

#define CH 8        // steps per chunk
#define NCHK 25     // 200 / 8

__launch_bounds__(320, 1)
__global__ void scan_rnn(const unsigned short* __restrict__ preT,
                         const float* __restrict__ Whh1,
                         const float* __restrict__ bih1,
                         const float* __restrict__ bhh1,
                         const float* __restrict__ Wih2,
                         const float* __restrict__ Whh2,
                         const float* __restrict__ bih2,
                         const float* __restrict__ bhh2,
                         const float* __restrict__ Wfc,
                         const float* __restrict__ bfc,
                         const float* __restrict__ mask1,
                         const float* __restrict__ mask2,
                         float* __restrict__ out)
{
    __shared__ alignas(16) float h1_s[2][104];    // [100..103] zero pad
    __shared__ alignas(16) float c_s[2][120];     // [0..99]=o1, [100..119]=h2
    __shared__ alignas(16) float h2f_s[H2];
    __shared__ alignas(16) float m_lds[2][CH * H1];   // mask1 chunks (f32)
    __shared__ alignas(16) float p_lds[2][CH * H1];   // pre1 chunks (f32)

    const int tid = threadIdx.x;
    const int b   = blockIdx.x;
    const float* m1b = mask1 + (size_t)b * TT * H1;
    const unsigned short* pTb = preT + (size_t)b * TT * H1;   // row-major [t][h]

    const int h = tid >> 1;
    const int p = tid & 1;
    const bool l1t = (tid < 200);
    const bool l2t = (tid >= 256 && tid < 256 + 2 * H2);   // wave 4 only
    const int k2 = (tid - 256) >> 1;
    const int p3 = (tid - 256) & 1;

    float4 w00{}, w01{}, w02{}, w03{}, w04{}, w05{}, w06{}, w07{},
           w08{}, w09{}, w10{}, w11{}, w12{}, w13{}, w14{};
    float b1 = 0.f, b2 = 0.f;

    if (l1t) {
        const float* wr = Whh1 + h * H1 + p * 52;
        w00 = *(const float4*)(wr +  0); w01 = *(const float4*)(wr +  4);
        w02 = *(const float4*)(wr +  8); w03 = *(const float4*)(wr + 12);
        w04 = *(const float4*)(wr + 16); w05 = *(const float4*)(wr + 20);
        w06 = *(const float4*)(wr + 24); w07 = *(const float4*)(wr + 28);
        w08 = *(const float4*)(wr + 32); w09 = *(const float4*)(wr + 36);
        w10 = *(const float4*)(wr + 40); w11 = *(const float4*)(wr + 44);
        if (p == 0) { w12 = *(const float4*)(wr + 48); b1 = bih1[h] + bhh1[h]; }
    } else if (l2t) {
        if (p3 == 0) {
            const float* wr = Wih2 + k2 * H1;           // [0..59]
            w00 = *(const float4*)(wr +  0); w01 = *(const float4*)(wr +  4);
            w02 = *(const float4*)(wr +  8); w03 = *(const float4*)(wr + 12);
            w04 = *(const float4*)(wr + 16); w05 = *(const float4*)(wr + 20);
            w06 = *(const float4*)(wr + 24); w07 = *(const float4*)(wr + 28);
            w08 = *(const float4*)(wr + 32); w09 = *(const float4*)(wr + 36);
            w10 = *(const float4*)(wr + 40); w11 = *(const float4*)(wr + 44);
            w12 = *(const float4*)(wr + 48); w13 = *(const float4*)(wr + 52);
            w14 = *(const float4*)(wr + 56);
            b2 = bih2[k2] + bhh2[k2];
        } else {
            const float* wr = Wih2 + k2 * H1 + 60;      // [60..99]
            w00 = *(const float4*)(wr +  0); w01 = *(const float4*)(wr +  4);
            w02 = *(const float4*)(wr +  8); w03 = *(const float4*)(wr + 12);
            w04 = *(const float4*)(wr + 16); w05 = *(const float4*)(wr + 20);
            w06 = *(const float4*)(wr + 24); w07 = *(const float4*)(wr + 28);
            w08 = *(const float4*)(wr + 32); w09 = *(const float4*)(wr + 36);
            const float* wh = Whh2 + k2 * H2;           // h2 part [100..119]
            w10 = *(const float4*)(wh +  0); w11 = *(const float4*)(wh +  4);
            w12 = *(const float4*)(wh +  8); w13 = *(const float4*)(wh + 12);
            w14 = *(const float4*)(wh + 16);
        }
    }

    for (int i = tid; i < 104; i += 320) { h1_s[0][i] = 0.f; h1_s[1][i] = 0.f; }
    for (int i = tid; i < 120; i += 320) { c_s[0][i] = 0.f; c_s[1][i] = 0.f; }

    // stage chunk 0 into buffer 0 (t = 0..7): one wide load per thread
    if (tid < 200) {
        const float4 mv = *(const float4*)&m1b[tid * 4];
        *(float4*)&m_lds[0][tid * 4] = mv;
    } else if (tid < 300) {
        const s16x8 pv = *(const s16x8*)&pTb[(tid - 200) * 8];
        float* dst = &p_lds[0][(tid - 200) * 8];
        *(float4*)dst       = make_float4(bf2f(pv[0]), bf2f(pv[1]), bf2f(pv[2]), bf2f(pv[3]));
        *(float4*)(dst + 4) = make_float4(bf2f(pv[4]), bf2f(pv[5]), bf2f(pv[6]), bf2f(pv[7]));
    }
    __syncthreads();

    int buf = 0;
    for (int c = 0; c < NCHK; ++c) {
        const bool more = (c + 1 < NCHK);
        float4 mst{}; s16x8 pst{};

        #pragma unroll
        for (int u = 0; u < CH; ++u) {
            const int t = c * CH + u;
            const int cur = t & 1, nxt = cur ^ 1;

            if (u > 0) STEP_BARRIER();         // LDS-only sync; no vmcnt drain

            if (u == 0 && more) {              // issue next chunk's loads;
                const int base = (c + 1) * (CH * H1);   // stay in flight 7 steps
                if (tid < 200)      mst = *(const float4*)&m1b[base + tid * 4];
                else if (tid < 300) pst = *(const s16x8*)&pTb[base + (tid - 200) * 8];
            }

            if (l1t) {
                float a0 = (p == 0) ? (p_lds[buf][u * H1 + h] + b1) : 0.f;
                const float mv = (p == 1) ? m_lds[buf][u * H1 + h] : 0.f;
                float a1 = 0.f, a2 = 0.f, a3 = 0.f;
                const float* hb = &h1_s[cur][p * 52];
                FMA4(w00, hb +  0); FMA4(w01, hb +  4); FMA4(w02, hb +  8);
                FMA4(w03, hb + 12); FMA4(w04, hb + 16); FMA4(w05, hb + 20);
                FMA4(w06, hb + 24); FMA4(w07, hb + 28); FMA4(w08, hb + 32);
                FMA4(w09, hb + 36); FMA4(w10, hb + 40); FMA4(w11, hb + 44);
                FMA4(w12, hb + 48);
                float part = (a0 + a1) + (a2 + a3);
                float tot  = part + __shfl_xor(part, 1);
                tot = fmaxf(tot, 0.f);                       // h1(t)
                if (p == 0) h1_s[nxt][h] = tot;
                else        c_s[nxt][h] = tot * mv;          // o1(t)
            }

            if (l2t && t >= 1) {
                float a0 = (p3 == 0) ? b2 : 0.f;
                float a1 = 0.f, a2 = 0.f, a3 = 0.f;
                const float* cb = &c_s[cur][p3 * 60];
                FMA4(w00, cb +  0); FMA4(w01, cb +  4); FMA4(w02, cb +  8);
                FMA4(w03, cb + 12); FMA4(w04, cb + 16); FMA4(w05, cb + 20);
                FMA4(w06, cb + 24); FMA4(w07, cb + 28); FMA4(w08, cb + 32);
                FMA4(w09, cb + 36); FMA4(w10, cb + 40); FMA4(w11, cb + 44);
                FMA4(w12, cb + 48); FMA4(w13, cb + 52); FMA4(w14, cb + 56);
                float part = (a0 + a1) + (a2 + a3);
                part += __shfl_xor(part, 1);
                const float h2v = fmaxf(part, 0.f);          // h2(t-1)
                if (p3 == 0) c_s[nxt][100 + k2] = h2v;
            }
        }

        // write staged chunk into the other buffer (latency fully elapsed;
        // compiler inserts the vmcnt wait before mst/pst use automatically)
        if (more) {
            if (tid < 200) {
                *(float4*)&m_lds[buf ^ 1][tid * 4] = mst;
            } else if (tid < 300) {
                float* dst = &p_lds[buf ^ 1][(tid - 200) * 8];
                *(float4*)dst       = make_float4(bf2f(pst[0]), bf2f(pst[1]), bf2f(pst[2]), bf2f(pst[3]));
                *(float4*)(dst + 4) = make_float4(bf2f(pst[4]), bf2f(pst[5]), bf2f(pst[6]), bf2f(pst[7]));
            }
            buf ^= 1;
        }
        __syncthreads();                        // chunk boundary: full fence
    }

    // epilogue t = TT: layer2 computes h2(199) from o1(199), h2(198)
    {
        const int cur = TT & 1;                              // 0
        if (l2t) {
            float a0 = (p3 == 0) ? b2 : 0.f;
            float a1 = 0.f, a2 = 0.f, a3 = 0.f;
            const float* cb = &c_s[cur][p3 * 60];
            FMA4(w00, cb +  0); FMA4(w01, cb +  4); FMA4(w02, cb +  8);
            FMA4(w03, cb + 12); FMA4(w04, cb + 16); FMA4(w05, cb + 20);
            FMA4(w06, cb + 24); FMA4(w07, cb + 28); FMA4(w08, cb + 32);
            FMA4(w09, cb + 36); FMA4(w10, cb + 40); FMA4(w11, cb + 44);
            FMA4(w12, cb + 48); FMA4(w13, cb + 52); FMA4(w14, cb + 56);
            float part = (a0 + a1) + (a2 + a3);
            part += __shfl_xor(part, 1);
            if (p3 == 0) h2f_s[k2] = fmaxf(part, 0.f);       // h2(199)
        }
        __syncthreads();
    }

    if (tid < NO) {
        const float* m2 = mask2 + ((size_t)b * TT + (TT - 1)) * H2;
        float s = bfc[tid];
        #pragma unroll
        for (int k = 0; k < H2; ++k)
            s = fmaf(Wfc[tid * H2 + k], h2f_s[k] * m2[k], s);
        out[b * NO + tid] = s;
    }
}

extern "C" void kernel_launch(void* const* d_in, const int* in_sizes, int n_in,
                              void* d_out, int out_size, void* d_ws, size_t ws_size,
                              hipStream_t stream) {
    const float* x     = (const float*)d_in[0];
    const float* Wih1  = (const float*)d_in[1];
    const float* Whh1  = (const float*)d_in[2];
    const float* bih1  = (const float*)d_in[3];
    const float* bhh1  = (const float*)d_in[4];
    const float* Wih2  = (const float*)d_in[5];
    const float* Whh2  = (const float*)d_in[6];
    const float* bih2  = (const float*)d_in[7];
    const float* bhh2  = (const float*)d_in[8];
    const float* Wfc   = (const float*)d_in[9];
    const float* bfc   = (const float*)d_in[10];
    const float* mask1 = (const float*)d_in[11];
    const float* mask2 = (const float*)d_in[12];
    float* out = (float*)d_out;

    unsigned short* preT = (unsigned short*)d_ws;                     // 10,240,000 B
    unsigned short* w_ws = (unsigned short*)((char*)d_ws + 10240000); //    286,720 B

    prep_w  <<<dim3((WR * KPAD / 4 + 255) / 256), dim3(256), 0, stream>>>(Wih1, w_ws);
    gemm_pre<<<dim3(GRID_A), dim3(256), 0, stream>>>(x, w_ws, preT);
    scan_rnn<<<dim3(NB), dim3(320), 0, stream>>>(preT, Whh1, bih1, bhh1,
                                                 Wih2, Whh2, bih2, bhh2,
                                                 Wfc, bfc, mask1, mask2, out);
}